// Round 1
// baseline (139.072 us; speedup 1.0000x reference)
//
#include <hip/hip_runtime.h>
#include <math.h>

#define BB 8
#define CC 128
#define NN 4096   // W*H

typedef _Float16 f16;
typedef _Float16 f16x4v __attribute__((ext_vector_type(4)));
typedef _Float16 f16x8 __attribute__((ext_vector_type(8)));
typedef float f32x4v __attribute__((ext_vector_type(4)));
typedef float f32x16 __attribute__((ext_vector_type(16)));

#if __has_builtin(__builtin_amdgcn_exp2f)
#define EXP2(x) __builtin_amdgcn_exp2f(x)
#else
#define EXP2(x) __expf((x)*0.69314718056f)
#endif

// Q rows pre-scaled by 0.25*log2(e): softmax exp is one native v_exp_f32;
// the -SHIFT bias rides in the MFMA C operand.
#define QSCALE 0.360673760222f   // 0.25 * log2(e)
#define SHIFT  5.770780163555f   // 4.0 * log2(e)

// Wf scratch lives in the tail of d_out (attn rewrites d_out afterwards).
#define WF_BYTES 65536

// ---------------------------------------------------------------------------
// prep: stack Wq*QSCALE (rows 0-15), Wk (16-31), Wv (32-159) as f16 in
// 32x32x16 A-fragment order. biasS f32[160] likewise stacked.
// ---------------------------------------------------------------------------
__global__ __launch_bounds__(256)
void prep_kernel(const float* __restrict__ Wq, const float* __restrict__ bq,
                 const float* __restrict__ Wk, const float* __restrict__ bk,
                 const float* __restrict__ Wv, const float* __restrict__ bv,
                 f16* __restrict__ Wf, float* __restrict__ biasS)
{
    const int tg = blockIdx.x*256 + threadIdx.x;   // 0..2559
    if (tg < 2560) {
        const int mt = tg >> 9, ks = (tg >> 6) & 7, l = tg & 63;
        const int n32 = l & 31, h = l >> 5;
        const int r = mt*32 + n32;
        f16x8 v8;
        #pragma unroll
        for (int i = 0; i < 8; i++) {
            int c = ks*16 + 8*h + i;
            float wv_;
            if (r < 16)      wv_ = QSCALE * Wq[r*CC + c];
            else if (r < 32) wv_ = Wk[(r-16)*CC + c];
            else             wv_ = Wv[(r-32)*CC + c];
            v8[i] = (f16)wv_;
        }
        *(f16x8*)&Wf[(size_t)tg*8] = v8;
    }
    if (blockIdx.x == 0 && threadIdx.x < 160) {
        int r = threadIdx.x;
        biasS[r] = r < 16 ? QSCALE*bq[r] : (r < 32 ? bk[r-16] : bv[r-32]);
    }
}

// ---------------------------------------------------------------------------
// Projection as MFMA mini-GEMM: OUT[160][128px] = Wst(160x128) * x(128x128px).
// grid 256 (b = bx&7, pt = bx>>3), block 256 = 4 waves, wave = 32-pixel
// n-tile, K=128 (8 ksteps), 40 MFMAs/wave. Non-temporal x loads keep L2 for
// Qt/Kt/Vf. Epilogue: Qt/Kt pixel-major; V via LDS -> sigma-ordered Vf:
//   Vf[b][kt64][frag=kc*4+ct][l][i] =
//     V[c=ct*32+(l&31)][key=kt64*64 + kc*16 + (i&3)+8*(i>>2)+4*(l>>5)]
// ---------------------------------------------------------------------------
__global__ __launch_bounds__(256)
void proj_kernel(const float* __restrict__ x, const f16* __restrict__ Wf,
                 const float* __restrict__ biasS,
                 f16* __restrict__ Qt, f16* __restrict__ Kt, f16* __restrict__ Vf)
{
    __shared__ __align__(16) f16 Vl[CC*140];   // 35 KB, stride 140 halfs

    const int tid  = threadIdx.x;
    const int lane = tid & 63;
    const int wv   = tid >> 6;
    const int b    = blockIdx.x & 7;
    const int pt   = blockIdx.x >> 3;      // 0..31
    const int n32  = lane & 31;
    const int half = lane >> 5;
    const int p    = pt*128 + wv*32 + n32;

    const float* xp = x + (size_t)b*CC*NN + p;
    f16x8 xf[8];
    #pragma unroll
    for (int ks = 0; ks < 8; ks++) {
        float xv[8];
        #pragma unroll
        for (int i = 0; i < 8; i++)
            xv[i] = __builtin_nontemporal_load(&xp[(size_t)(ks*16 + 8*half + i)*NN]);
        #pragma unroll
        for (int i = 0; i < 8; i++) xf[ks][i] = (f16)xv[i];
    }

    f32x16 acc[5];
    #pragma unroll
    for (int mt = 0; mt < 5; mt++) acc[mt] = (f32x16)0.0f;
    #pragma unroll
    for (int ks = 0; ks < 8; ks++) {
        #pragma unroll
        for (int mt = 0; mt < 5; mt++) {
            f16x8 wfr = *(const f16x8*)&Wf[((size_t)(mt*8 + ks)*64 + lane)*8];
            acc[mt] = __builtin_amdgcn_mfma_f32_32x32x16_f16(wfr, xf[ks], acc[mt], 0, 0, 0);
        }
    }

    #pragma unroll
    for (int mt = 0; mt < 5; mt++) {
        #pragma unroll
        for (int q = 0; q < 4; q++) {
            float4 b4 = *(const float4*)&biasS[mt*32 + q*8 + 4*half];
            acc[mt][q*4+0] += b4.x; acc[mt][q*4+1] += b4.y;
            acc[mt][q*4+2] += b4.z; acc[mt][q*4+3] += b4.w;
        }
    }

    // mt0: rows 0-15 = Q, 16-31 = K
    {
        size_t qkoff = ((size_t)b*NN + p)*16;
        f16x4v s0, s1, s2, s3;
        #pragma unroll
        for (int i = 0; i < 4; i++) {
            s0[i] = (f16)acc[0][i];    s1[i] = (f16)acc[0][4+i];
            s2[i] = (f16)acc[0][8+i];  s3[i] = (f16)acc[0][12+i];
        }
        *(f16x4v*)&Qt[qkoff + 4*half]     = s0;
        *(f16x4v*)&Qt[qkoff + 8 + 4*half] = s1;
        *(f16x4v*)&Kt[qkoff + 4*half]     = s2;
        *(f16x4v*)&Kt[qkoff + 8 + 4*half] = s3;
    }

    // mt1-4: V channels -> LDS [c][local pixel]
    #pragma unroll
    for (int mt = 1; mt < 5; mt++) {
        #pragma unroll
        for (int g = 0; g < 16; g++) {
            int c = (mt-1)*32 + (g & 3) + 8*(g >> 2) + 4*half;
            Vl[c*140 + wv*32 + n32] = (f16)acc[mt][g];
        }
    }
    __syncthreads();

    // sigma-ordered Vf writeout
    #pragma unroll
    for (int pass = 0; pass < 8; pass++) {
        int item = pass*256 + tid;
        int l    = item & 63;
        int f    = (item >> 6) & 15;       // kc*4 + ct
        int ktl  = item >> 10;             // 0..1 (64-px tile within block)
        int c16  = f >> 2, ct = f & 3;
        int li   = l & 31, h2 = l >> 5;
        const f16* src = &Vl[(ct*32 + li)*140 + ktl*64 + c16*16 + 4*h2];
        f16x4v lo = *(const f16x4v*)&src[0];
        f16x4v hi = *(const f16x4v*)&src[8];
        f16x8 v8;
        #pragma unroll
        for (int i = 0; i < 4; i++) { v8[i] = lo[i]; v8[4+i] = hi[i]; }
        int ktg = pt*2 + ktl;              // 64-key tile index
        *(f16x8*)&Vf[((((size_t)b*64 + ktg)*16 + c16*4 + ct)*64 + l)*8] = v8;
    }
}

// ---------------------------------------------------------------------------
// Attention r9: 64 queries/block (grid 512, b = bx&7 keeps XCD affinity,
// qt = bx>>3 -> 64-query tile). Block 256 = 4 waves arranged as a
// 2-way KEY split x 2-way CHANNEL split:
//   wave wv: cp = wv&1 (channel tiles ct in {2cp,2cp+1}),
//            kh = wv>>1 (key tiles kt = kh, kh+2, ...).
// Rationale (rocprof): attn was L2-BW bound -- 1.18 GB L2 reads/dispatch at
// 20.6 TB/s sustained = the 57 us. Each V fragment now feeds TWO PV MFMAs
// (q-tiles A,B) -> read traffic 0.65 GB (-45%). The wave pair recomputes
// QK^T + exp redundantly (trans pipe is idle anyway) to keep VGPRs ~200:
// of[2][2]=64 + vpf[8]=32 + pf[2][4]=32 + K/Q/ps/temps, fits 2 blocks/CU.
// Main loop stays LDS-free/barrier-free with full register prefetch.
// ---------------------------------------------------------------------------
__global__ __launch_bounds__(256, 2)
void attn_kernel(const f16* __restrict__ Qt, const f16* __restrict__ Kt,
                 const f16* __restrict__ Vf, float* __restrict__ out)
{
    __shared__ __align__(16) unsigned char lds_raw[53504];
    // [0, 18432):     2 combine regions (64 lanes x 144B), region cp
    // [18432, 18688): ls_inv[64] f32
    // [18688, 53504): Tb f32 [128 c][68]  (pad 68 -> ~4-way instead of 32-way)

    const int tid  = threadIdx.x;
    const int lane = tid & 63;
    const int wv   = tid >> 6;
    const int cp   = wv & 1;           // channel pair: ct in {2cp, 2cp+1}
    const int kh   = wv >> 1;          // key half: kt = kh (mod 2)
    const int b    = blockIdx.x & 7;
    const int qt   = blockIdx.x >> 3;  // 0..63
    const int q0   = qt*64;
    const int n32  = lane & 31;
    const int half = lane >> 5;

    const f16* vb = Vf + (size_t)b*64*16*512;
    const f16* kb = Kt + (size_t)b*NN*16;
    const f16x8 qfA = *(const f16x8*)&Qt[((size_t)b*NN + q0 + n32)*16 + half*8];
    const f16x8 qfB = *(const f16x8*)&Qt[((size_t)b*NN + q0 + 32 + n32)*16 + half*8];

    f32x16 ofA[2], ofB[2];
    #pragma unroll
    for (int c = 0; c < 2; c++) { ofA[c] = (f32x16)0.0f; ofB[c] = (f32x16)0.0f; }
    float psA[4] = {0.f, 0.f, 0.f, 0.f};
    float psB[4] = {0.f, 0.f, 0.f, 0.f};

    // prime the pipeline: K + this wave's 8 V fragments for kt = kh
    f16x8 kf0 = *(const f16x8*)&kb[((size_t)kh*64 + n32)*16 + half*8];
    f16x8 kf1 = *(const f16x8*)&kb[((size_t)kh*64 + 32 + n32)*16 + half*8];
    f16x8 vpf[8];
    {
        const f16* vt = vb + (size_t)kh*8192;
        #pragma unroll
        for (int kc = 0; kc < 4; kc++)
            #pragma unroll
            for (int j = 0; j < 2; j++)
                vpf[kc*2+j] = *(const f16x8*)&vt[((size_t)(kc*4 + 2*cp + j)*64 + lane)*8];
    }

    for (int kt = kh; kt < NN/64; kt += 2) {
        const int ktn = (kt + 2 < NN/64) ? kt + 2 : kt;
        f16x8 kf0n = *(const f16x8*)&kb[((size_t)ktn*64 + n32)*16 + half*8];
        f16x8 kf1n = *(const f16x8*)&kb[((size_t)ktn*64 + 32 + n32)*16 + half*8];

        // q-tile A: S^T = K * qA, P = 2^(S - SHIFT)
        f16x8 pfA[4];
        {
            f32x16 St0 = __builtin_amdgcn_mfma_f32_32x32x16_f16(kf0, qfA, (f32x16)(-SHIFT), 0, 0, 0);
            f32x16 St1 = __builtin_amdgcn_mfma_f32_32x32x16_f16(kf1, qfA, (f32x16)(-SHIFT), 0, 0, 0);
            #pragma unroll
            for (int g = 0; g < 16; g++) {
                float e0 = EXP2(St0[g]); psA[g & 3] += e0; pfA[(g >> 3)][g & 7]     = (f16)e0;
                float e1 = EXP2(St1[g]); psA[g & 3] += e1; pfA[2 + (g >> 3)][g & 7] = (f16)e1;
            }
        }
        // q-tile B
        f16x8 pfB[4];
        {
            f32x16 St0 = __builtin_amdgcn_mfma_f32_32x32x16_f16(kf0, qfB, (f32x16)(-SHIFT), 0, 0, 0);
            f32x16 St1 = __builtin_amdgcn_mfma_f32_32x32x16_f16(kf1, qfB, (f32x16)(-SHIFT), 0, 0, 0);
            #pragma unroll
            for (int g = 0; g < 16; g++) {
                float e0 = EXP2(St0[g]); psB[g & 3] += e0; pfB[(g >> 3)][g & 7]     = (f16)e0;
                float e1 = EXP2(St1[g]); psB[g & 3] += e1; pfB[2 + (g >> 3)][g & 7] = (f16)e1;
            }
        }

        const f16* vtn = vb + (size_t)ktn*8192;
        #pragma unroll
        for (int kc = 0; kc < 4; kc++) {
            #pragma unroll
            for (int j = 0; j < 2; j++) {
                const int ii = kc*2 + j;
                f16x8 vc = vpf[ii];
                vpf[ii] = *(const f16x8*)&vtn[((size_t)(kc*4 + 2*cp + j)*64 + lane)*8];  // prefetch kt+2
                ofA[j] = __builtin_amdgcn_mfma_f32_32x32x16_f16(pfA[kc], vc, ofA[j], 0, 0, 0);
                ofB[j] = __builtin_amdgcn_mfma_f32_32x32x16_f16(pfB[kc], vc, ofB[j], 0, 0, 0);
            }
        }
        kf0 = kf0n; kf1 = kf1n;
    }

    // per-lane softmax denominators (this wave's key half; query q0[+32]+n32)
    float lsA = (psA[0] + psA[1]) + (psA[2] + psA[3]);
    lsA += __shfl_xor(lsA, 32);
    float lsB = (psB[0] + psB[1]) + (psB[2] + psB[3]);
    lsB += __shfl_xor(lsB, 32);

    // ---- combine the 2-way key split (wave pairs (0,2) and (1,3)) ----
    __syncthreads();
    if (wv >= 2) {
        unsigned char* base = lds_raw + (size_t)cp*9216 + (size_t)lane*144;
        #pragma unroll
        for (int a = 0; a < 4; a++) {        // a = qtsel*2 + ctl
            #pragma unroll
            for (int h = 0; h < 2; h++) {
                f16x8 t;
                #pragma unroll
                for (int jj = 0; jj < 8; jj++)
                    t[jj] = (f16)((a < 2 ? ofA[a & 1] : ofB[a & 1])[h*8 + jj]);
                *(f16x8*)(base + a*32 + h*16) = t;
            }
        }
        *(float*)(base + 128) = lsA;
        *(float*)(base + 132) = lsB;
    }
    __syncthreads();
    if (wv < 2) {
        unsigned char* base = lds_raw + (size_t)cp*9216 + (size_t)lane*144;
        #pragma unroll
        for (int a = 0; a < 4; a++) {
            #pragma unroll
            for (int h = 0; h < 2; h++) {
                f16x8 t = *(const f16x8*)(base + a*32 + h*16);
                #pragma unroll
                for (int jj = 0; jj < 8; jj++) {
                    float v = (float)t[jj];
                    if (a < 2) ofA[a & 1][h*8 + jj] += v;
                    else       ofB[a & 1][h*8 + jj] += v;
                }
            }
        }
        if (wv == 0) {
            float lsA2 = *(const float*)(base + 128);
            float lsB2 = *(const float*)(base + 132);
            float* ls_inv = (float*)(lds_raw + 18432);
            if (lane < 32) {
                ls_inv[n32]      = 1.f / (lsA + lsA2);
                ls_inv[32 + n32] = 1.f / (lsB + lsB2);
            }
        }
    }
    __syncthreads();

    // normalize + transpose into Tb[c][q] (waves 0,1 own 64 channels each)
    if (wv < 2) {
        const float* ls_inv = (const float*)(lds_raw + 18432);
        float* Tb = (float*)(lds_raw + 18688);
        #pragma unroll
        for (int qts = 0; qts < 2; qts++) {
            #pragma unroll
            for (int j = 0; j < 4; j++) {
                f32x4v iv = *(const f32x4v*)&ls_inv[qts*32 + 8*j + 4*half];
                #pragma unroll
                for (int ctl = 0; ctl < 2; ctl++) {
                    const int c = (2*cp + ctl)*32 + n32;
                    f32x4v o;
                    #pragma unroll
                    for (int e = 0; e < 4; e++)
                        o[e] = (qts ? ofB[ctl] : ofA[ctl])[4*j + e] * iv[e];
                    *(f32x4v*)&Tb[(size_t)c*68 + qts*32 + 8*j + 4*half] = o;
                }
            }
        }
    }
    __syncthreads();
    {
        const float* Tb = (const float*)(lds_raw + 18688);
        #pragma unroll
        for (int it = 0; it < 8; it++) {
            int idx = it*256 + tid;
            int c = idx >> 4, qg = idx & 15;
            f32x4v v = *(const f32x4v*)&Tb[(size_t)c*68 + qg*4];
            // non-temporal: keep the 16 MB output stream out of L2
            __builtin_nontemporal_store(v,
                (f32x4v*)&out[((size_t)b*CC + c)*NN + q0 + qg*4]);
        }
    }
}

extern "C" void kernel_launch(void* const* d_in, const int* in_sizes, int n_in,
                              void* d_out, int out_size, void* d_ws, size_t ws_size,
                              hipStream_t stream) {
    const float* x  = (const float*)d_in[0];
    const float* Wq = (const float*)d_in[1];
    const float* bq = (const float*)d_in[2];
    const float* Wk = (const float*)d_in[3];
    const float* bk = (const float*)d_in[4];
    const float* Wv = (const float*)d_in[5];
    const float* bv = (const float*)d_in[6];
    float* out = (float*)d_out;

    // workspace: Qt,Kt f16 [B][N][16] (1MB each), Vf f16 sigma-fragments (8MB)
    f16* Qw = (f16*)d_ws;
    f16* Kw = Qw + (size_t)BB*NN*16;
    f16* Vw = Kw + (size_t)BB*NN*16;
    unsigned char* tail = (unsigned char*)d_out + (size_t)out_size*4 - WF_BYTES;
    f16*   Wf    = (f16*)tail;
    float* biasS = (float*)(tail + 49152);

    hipLaunchKernelGGL(prep_kernel, dim3(10), dim3(256), 0, stream,
                       Wq, bq, Wk, bk, Wv, bv, Wf, biasS);
    hipLaunchKernelGGL(proj_kernel, dim3(256), dim3(256), 0, stream,
                       x, Wf, biasS, Qw, Kw, Vw);
    hipLaunchKernelGGL(attn_kernel, dim3(512), dim3(256), 0, stream,
                       Qw, Kw, Vw, out);
}

// Round 2
// 133.927 us; speedup vs baseline: 1.0384x; 1.0384x over previous
//
#include <hip/hip_runtime.h>
#include <math.h>

#define BB 8
#define CC 128
#define NN 4096   // W*H

typedef _Float16 f16;
typedef _Float16 f16x4v __attribute__((ext_vector_type(4)));
typedef _Float16 f16x8 __attribute__((ext_vector_type(8)));
typedef float f32x4v __attribute__((ext_vector_type(4)));
typedef float f32x16 __attribute__((ext_vector_type(16)));

#if __has_builtin(__builtin_amdgcn_exp2f)
#define EXP2(x) __builtin_amdgcn_exp2f(x)
#else
#define EXP2(x) __expf((x)*0.69314718056f)
#endif

// Q rows pre-scaled by 0.25*log2(e): softmax exp is one native v_exp_f32;
// the -SHIFT bias rides in the MFMA C operand.
#define QSCALE 0.360673760222f   // 0.25 * log2(e)
#define SHIFT  5.770780163555f   // 4.0 * log2(e)

// Wf scratch lives in the tail of d_out (attn rewrites d_out afterwards).
#define WF_BYTES 65536

// ---------------------------------------------------------------------------
// prep: stack Wq*QSCALE (rows 0-15), Wk (16-31), Wv (32-159) as f16 in
// 32x32x16 A-fragment order. biasS f32[160] likewise stacked.
// ---------------------------------------------------------------------------
__global__ __launch_bounds__(256)
void prep_kernel(const float* __restrict__ Wq, const float* __restrict__ bq,
                 const float* __restrict__ Wk, const float* __restrict__ bk,
                 const float* __restrict__ Wv, const float* __restrict__ bv,
                 f16* __restrict__ Wf, float* __restrict__ biasS)
{
    const int tg = blockIdx.x*256 + threadIdx.x;   // 0..2559
    if (tg < 2560) {
        const int mt = tg >> 9, ks = (tg >> 6) & 7, l = tg & 63;
        const int n32 = l & 31, h = l >> 5;
        const int r = mt*32 + n32;
        f16x8 v8;
        #pragma unroll
        for (int i = 0; i < 8; i++) {
            int c = ks*16 + 8*h + i;
            float wv_;
            if (r < 16)      wv_ = QSCALE * Wq[r*CC + c];
            else if (r < 32) wv_ = Wk[(r-16)*CC + c];
            else             wv_ = Wv[(r-32)*CC + c];
            v8[i] = (f16)wv_;
        }
        *(f16x8*)&Wf[(size_t)tg*8] = v8;
    }
    if (blockIdx.x == 0 && threadIdx.x < 160) {
        int r = threadIdx.x;
        biasS[r] = r < 16 ? QSCALE*bq[r] : (r < 32 ? bk[r-16] : bv[r-32]);
    }
}

// ---------------------------------------------------------------------------
// Projection as MFMA mini-GEMM: OUT[160][128px] = Wst(160x128) * x(128x128px).
// grid 256 (b = bx&7, pt = bx>>3), block 256 = 4 waves, wave = 32-pixel
// n-tile, K=128 (8 ksteps), 40 MFMAs/wave. Non-temporal x loads keep L2 for
// Qt/Kt/Vf. Epilogue: Qt/Kt pixel-major; V via LDS -> sigma-ordered Vf:
//   Vf[b][kt64][frag=kc*4+ct][l][i] =
//     V[c=ct*32+(l&31)][key=kt64*64 + kc*16 + (i&3)+8*(i>>2)+4*(l>>5)]
// ---------------------------------------------------------------------------
__global__ __launch_bounds__(256)
void proj_kernel(const float* __restrict__ x, const f16* __restrict__ Wf,
                 const float* __restrict__ biasS,
                 f16* __restrict__ Qt, f16* __restrict__ Kt, f16* __restrict__ Vf)
{
    __shared__ __align__(16) f16 Vl[CC*140];   // 35 KB, stride 140 halfs

    const int tid  = threadIdx.x;
    const int lane = tid & 63;
    const int wv   = tid >> 6;
    const int b    = blockIdx.x & 7;
    const int pt   = blockIdx.x >> 3;      // 0..31
    const int n32  = lane & 31;
    const int half = lane >> 5;
    const int p    = pt*128 + wv*32 + n32;

    const float* xp = x + (size_t)b*CC*NN + p;
    f16x8 xf[8];
    #pragma unroll
    for (int ks = 0; ks < 8; ks++) {
        float xv[8];
        #pragma unroll
        for (int i = 0; i < 8; i++)
            xv[i] = __builtin_nontemporal_load(&xp[(size_t)(ks*16 + 8*half + i)*NN]);
        #pragma unroll
        for (int i = 0; i < 8; i++) xf[ks][i] = (f16)xv[i];
    }

    f32x16 acc[5];
    #pragma unroll
    for (int mt = 0; mt < 5; mt++) acc[mt] = (f32x16)0.0f;
    #pragma unroll
    for (int ks = 0; ks < 8; ks++) {
        #pragma unroll
        for (int mt = 0; mt < 5; mt++) {
            f16x8 wfr = *(const f16x8*)&Wf[((size_t)(mt*8 + ks)*64 + lane)*8];
            acc[mt] = __builtin_amdgcn_mfma_f32_32x32x16_f16(wfr, xf[ks], acc[mt], 0, 0, 0);
        }
    }

    #pragma unroll
    for (int mt = 0; mt < 5; mt++) {
        #pragma unroll
        for (int q = 0; q < 4; q++) {
            float4 b4 = *(const float4*)&biasS[mt*32 + q*8 + 4*half];
            acc[mt][q*4+0] += b4.x; acc[mt][q*4+1] += b4.y;
            acc[mt][q*4+2] += b4.z; acc[mt][q*4+3] += b4.w;
        }
    }

    // mt0: rows 0-15 = Q, 16-31 = K
    {
        size_t qkoff = ((size_t)b*NN + p)*16;
        f16x4v s0, s1, s2, s3;
        #pragma unroll
        for (int i = 0; i < 4; i++) {
            s0[i] = (f16)acc[0][i];    s1[i] = (f16)acc[0][4+i];
            s2[i] = (f16)acc[0][8+i];  s3[i] = (f16)acc[0][12+i];
        }
        *(f16x4v*)&Qt[qkoff + 4*half]     = s0;
        *(f16x4v*)&Qt[qkoff + 8 + 4*half] = s1;
        *(f16x4v*)&Kt[qkoff + 4*half]     = s2;
        *(f16x4v*)&Kt[qkoff + 8 + 4*half] = s3;
    }

    // mt1-4: V channels -> LDS [c][local pixel]
    #pragma unroll
    for (int mt = 1; mt < 5; mt++) {
        #pragma unroll
        for (int g = 0; g < 16; g++) {
            int c = (mt-1)*32 + (g & 3) + 8*(g >> 2) + 4*half;
            Vl[c*140 + wv*32 + n32] = (f16)acc[mt][g];
        }
    }
    __syncthreads();

    // sigma-ordered Vf writeout
    #pragma unroll
    for (int pass = 0; pass < 8; pass++) {
        int item = pass*256 + tid;
        int l    = item & 63;
        int f    = (item >> 6) & 15;       // kc*4 + ct
        int ktl  = item >> 10;             // 0..1 (64-px tile within block)
        int c16  = f >> 2, ct = f & 3;
        int li   = l & 31, h2 = l >> 5;
        const f16* src = &Vl[(ct*32 + li)*140 + ktl*64 + c16*16 + 4*h2];
        f16x4v lo = *(const f16x4v*)&src[0];
        f16x4v hi = *(const f16x4v*)&src[8];
        f16x8 v8;
        #pragma unroll
        for (int i = 0; i < 4; i++) { v8[i] = lo[i]; v8[4+i] = hi[i]; }
        int ktg = pt*2 + ktl;              // 64-key tile index
        *(f16x8*)&Vf[((((size_t)b*64 + ktg)*16 + c16*4 + ct)*64 + l)*8] = v8;
    }
}

// ---------------------------------------------------------------------------
// Attention r10: kill the QK/exp redundancy via LDS P-exchange.
// rocprof r9: VALUBusy 52% (28.8us) > MfmaUtil 33% (18us); L2 only 12 of
// 34.5 TB/s -> the wave-pair's duplicated QK^T+exp is the tallest pipe.
// Grid 512 (b = bx&7, qt = bx>>3 -> 64 queries), block 256 = 4 waves:
//   wave w: cp = w&1 (channel pair ct in {2cp,2cp+1}, AND q-tile owner:
//           cp==0 -> tile A, cp==1 -> tile B), kh = w>>1 (key half).
// Per iter each wave computes QK^T+exp for ITS q-tile only (2 MFMAs + 32
// exps, was 4 + 64), writes its 4 P-frags (64B/lane, contiguous b128,
// conflict-free) to double-buffered LDS, one __syncthreads, reads the
// partner's frags (same-lane round-trip; identical lane layout). PV block
// unchanged: every V fragment still feeds both q-tiles. The barrier's
// implicit vmem drain is ~free: K prefetch issued at iter top, V prefetch
// in the previous PV, both >450 cyc before the barrier.
// ---------------------------------------------------------------------------
__global__ __launch_bounds__(256, 2)
void attn_kernel(const f16* __restrict__ Qt, const f16* __restrict__ Kt,
                 const f16* __restrict__ Vf, float* __restrict__ out)
{
    __shared__ __align__(16) unsigned char lds_raw[53504];
    // main loop:  Pex [4 waves][2 buf][4 kc][64 lanes][16B] = 32 KB at 0
    // epilogue:   combine regions 2 x 9216 at 0; ls_inv f32[64] at 18432;
    //             Tb f32[128][68] at 18688 (all alias Pex; phases barriered)

    const int tid  = threadIdx.x;
    const int lane = tid & 63;
    const int w    = tid >> 6;
    const int cp   = w & 1;            // channel pair + q-tile ownership
    const int kh   = w >> 1;           // key half: kt = kh (mod 2)
    const int b    = blockIdx.x & 7;
    const int qt   = blockIdx.x >> 3;  // 0..63
    const int q0   = qt*64;
    const int n32  = lane & 31;
    const int half = lane >> 5;

    const f16* vb = Vf + (size_t)b*64*16*512;
    const f16* kb = Kt + (size_t)b*NN*16;
    // own q-tile only: A (q0..q0+31) if cp==0, B (q0+32..) if cp==1
    const f16x8 qf = *(const f16x8*)&Qt[((size_t)b*NN + q0 + cp*32 + n32)*16 + half*8];

    f32x16 ofA[2], ofB[2];
    #pragma unroll
    for (int c = 0; c < 2; c++) { ofA[c] = (f32x16)0.0f; ofB[c] = (f32x16)0.0f; }
    float ps[4] = {0.f, 0.f, 0.f, 0.f};

    // prime the pipeline: K + this wave's 8 V fragments for kt = kh
    f16x8 kf0 = *(const f16x8*)&kb[((size_t)kh*64 + n32)*16 + half*8];
    f16x8 kf1 = *(const f16x8*)&kb[((size_t)kh*64 + 32 + n32)*16 + half*8];
    f16x8 vpf[8];
    {
        const f16* vt = vb + (size_t)kh*8192;
        #pragma unroll
        for (int kc = 0; kc < 4; kc++)
            #pragma unroll
            for (int j = 0; j < 2; j++)
                vpf[kc*2+j] = *(const f16x8*)&vt[((size_t)(kc*4 + 2*cp + j)*64 + lane)*8];
    }

    f16* Pex = (f16*)lds_raw;
    int pb = 0;

    for (int kt = kh; kt < NN/64; kt += 2) {
        const int ktn = (kt + 2 < NN/64) ? kt + 2 : kt;
        f16x8 kf0n = *(const f16x8*)&kb[((size_t)ktn*64 + n32)*16 + half*8];
        f16x8 kf1n = *(const f16x8*)&kb[((size_t)ktn*64 + 32 + n32)*16 + half*8];

        // own q-tile: S^T = K * qf, P = 2^(S - SHIFT)
        f16x8 po[4];
        {
            f32x16 St0 = __builtin_amdgcn_mfma_f32_32x32x16_f16(kf0, qf, (f32x16)(-SHIFT), 0, 0, 0);
            f32x16 St1 = __builtin_amdgcn_mfma_f32_32x32x16_f16(kf1, qf, (f32x16)(-SHIFT), 0, 0, 0);
            #pragma unroll
            for (int g = 0; g < 16; g++) {
                float e0 = EXP2(St0[g]); ps[g & 3] += e0; po[(g >> 3)][g & 7]     = (f16)e0;
                float e1 = EXP2(St1[g]); ps[g & 3] += e1; po[2 + (g >> 3)][g & 7] = (f16)e1;
            }
        }

        // ---- P exchange with partner wave (w^1): same kh, other q-tile ----
        {
            f16* wr = &Pex[((size_t)(w*2 + pb)*4*64 + lane)*8];
            #pragma unroll
            for (int kc = 0; kc < 4; kc++)
                *(f16x8*)&wr[kc*512] = po[kc];
        }
        __syncthreads();
        f16x8 pq[4];
        {
            const f16* rd = &Pex[((size_t)((w^1)*2 + pb)*4*64 + lane)*8];
            #pragma unroll
            for (int kc = 0; kc < 4; kc++)
                pq[kc] = *(const f16x8*)&rd[kc*512];
        }

        const f16* vtn = vb + (size_t)ktn*8192;
#define PV_BLOCK(PA, PB)                                                              \
        _Pragma("unroll")                                                             \
        for (int kc = 0; kc < 4; kc++) {                                              \
            _Pragma("unroll")                                                         \
            for (int j = 0; j < 2; j++) {                                             \
                const int ii = kc*2 + j;                                              \
                f16x8 vc = vpf[ii];                                                   \
                vpf[ii] = *(const f16x8*)&vtn[((size_t)(kc*4 + 2*cp + j)*64 + lane)*8]; \
                ofA[j] = __builtin_amdgcn_mfma_f32_32x32x16_f16(PA[kc], vc, ofA[j], 0, 0, 0); \
                ofB[j] = __builtin_amdgcn_mfma_f32_32x32x16_f16(PB[kc], vc, ofB[j], 0, 0, 0); \
            }                                                                         \
        }
        if (cp == 0) { PV_BLOCK(po, pq) }
        else         { PV_BLOCK(pq, po) }
#undef PV_BLOCK

        kf0 = kf0n; kf1 = kf1n; pb ^= 1;
    }

    // per-lane softmax denominator for own q-tile (this wave's key half)
    float ls = (ps[0] + ps[1]) + (ps[2] + ps[3]);
    ls += __shfl_xor(ls, 32);

    // ---- combine the 2-way key split (wave pairs (0,2) and (1,3)) ----
    __syncthreads();
    if (w >= 2) {
        unsigned char* base = lds_raw + (size_t)cp*9216 + (size_t)lane*144;
        #pragma unroll
        for (int a = 0; a < 4; a++) {        // a = qtsel*2 + ctl
            #pragma unroll
            for (int h = 0; h < 2; h++) {
                f16x8 t;
                #pragma unroll
                for (int jj = 0; jj < 8; jj++)
                    t[jj] = (f16)((a < 2 ? ofA[a & 1] : ofB[a & 1])[h*8 + jj]);
                *(f16x8*)(base + a*32 + h*16) = t;
            }
        }
        *(float*)(base + 128) = ls;          // own q-tile's denominator partial
    }
    __syncthreads();
    if (w < 2) {
        unsigned char* base = lds_raw + (size_t)cp*9216 + (size_t)lane*144;
        #pragma unroll
        for (int a = 0; a < 4; a++) {
            #pragma unroll
            for (int h = 0; h < 2; h++) {
                f16x8 t = *(const f16x8*)(base + a*32 + h*16);
                #pragma unroll
                for (int jj = 0; jj < 8; jj++) {
                    float v = (float)t[jj];
                    if (a < 2) ofA[a & 1][h*8 + jj] += v;
                    else       ofB[a & 1][h*8 + jj] += v;
                }
            }
        }
        ls += *(const float*)(base + 128);
        // lead wave (0,cp) now has the full denominator for q-tile cp
        float* ls_inv = (float*)(lds_raw + 18432);
        if (lane < 32) ls_inv[cp*32 + n32] = 1.f / ls;
    }
    __syncthreads();

    // normalize + transpose into Tb[c][q] (waves 0,1 own 64 channels each)
    if (w < 2) {
        const float* ls_inv = (const float*)(lds_raw + 18432);
        float* Tb = (float*)(lds_raw + 18688);
        #pragma unroll
        for (int qts = 0; qts < 2; qts++) {
            #pragma unroll
            for (int j = 0; j < 4; j++) {
                f32x4v iv = *(const f32x4v*)&ls_inv[qts*32 + 8*j + 4*half];
                #pragma unroll
                for (int ctl = 0; ctl < 2; ctl++) {
                    const int c = (2*cp + ctl)*32 + n32;
                    f32x4v o;
                    #pragma unroll
                    for (int e = 0; e < 4; e++)
                        o[e] = (qts ? ofB[ctl] : ofA[ctl])[4*j + e] * iv[e];
                    *(f32x4v*)&Tb[(size_t)c*68 + qts*32 + 8*j + 4*half] = o;
                }
            }
        }
    }
    __syncthreads();
    {
        const float* Tb = (const float*)(lds_raw + 18688);
        #pragma unroll
        for (int it = 0; it < 8; it++) {
            int idx = it*256 + tid;
            int c = idx >> 4, qg = idx & 15;
            f32x4v v = *(const f32x4v*)&Tb[(size_t)c*68 + qg*4];
            // non-temporal: keep the 16 MB output stream out of L2
            __builtin_nontemporal_store(v,
                (f32x4v*)&out[((size_t)b*CC + c)*NN + q0 + qg*4]);
        }
    }
}

extern "C" void kernel_launch(void* const* d_in, const int* in_sizes, int n_in,
                              void* d_out, int out_size, void* d_ws, size_t ws_size,
                              hipStream_t stream) {
    const float* x  = (const float*)d_in[0];
    const float* Wq = (const float*)d_in[1];
    const float* bq = (const float*)d_in[2];
    const float* Wk = (const float*)d_in[3];
    const float* bk = (const float*)d_in[4];
    const float* Wv = (const float*)d_in[5];
    const float* bv = (const float*)d_in[6];
    float* out = (float*)d_out;

    // workspace: Qt,Kt f16 [B][N][16] (1MB each), Vf f16 sigma-fragments (8MB)
    f16* Qw = (f16*)d_ws;
    f16* Kw = Qw + (size_t)BB*NN*16;
    f16* Vw = Kw + (size_t)BB*NN*16;
    unsigned char* tail = (unsigned char*)d_out + (size_t)out_size*4 - WF_BYTES;
    f16*   Wf    = (f16*)tail;
    float* biasS = (float*)(tail + 49152);

    hipLaunchKernelGGL(prep_kernel, dim3(10), dim3(256), 0, stream,
                       Wq, bq, Wk, bk, Wv, bv, Wf, biasS);
    hipLaunchKernelGGL(proj_kernel, dim3(256), dim3(256), 0, stream,
                       x, Wf, biasS, Qw, Kw, Vw);
    hipLaunchKernelGGL(attn_kernel, dim3(512), dim3(256), 0, stream,
                       Qw, Kw, Vw, out);
}